// Round 1
// baseline (110.927 us; speedup 1.0000x reference)
//
#include <hip/hip_runtime.h>

typedef __bf16 bf16_t;
typedef __bf16 bf16x8 __attribute__((ext_vector_type(8)));
typedef float  f32x4  __attribute__((ext_vector_type(4)));

#define Bdim 8
#define Ldim 2048
#define Ddim 256
#define MROWS 64
// Ut: [n][i] fp32, i in [0,80), padded stride 84 -> 86016 B
#define USTRIDE 84

// Build frag-major (B-operand) bf16 copies of weight and input_weight.
// Chunk (kt,nt) holds B[k=kt*32+quad*8+j][n=nt*16+(lane&15)], flat index
// e = ((kt*16+nt)*64 + lane)*8 + j.
__global__ void swz_kernel(const float* __restrict__ w,
                           const float* __restrict__ win,
                           bf16_t* __restrict__ wsw,
                           bf16_t* __restrict__ winsw) {
    int tid  = blockIdx.x * blockDim.x + threadIdx.x;  // 0..131071
    int mat  = tid >> 16;
    int e    = tid & 65535;
    int j    = e & 7;
    int lane = (e >> 3) & 63;
    int nt   = (e >> 9) & 15;
    int kt   = e >> 13;
    int c = lane & 15, q = lane >> 4;
    int k = kt * 32 + q * 8 + j;
    int n = nt * 16 + c;
    const float* src = mat ? win : w;
    bf16_t v = (bf16_t)src[k * Ddim + n];
    if (mat) winsw[e] = v; else wsw[e] = v;
}

__global__ __launch_bounds__(256, 1)
void rnn_kernel(const float* __restrict__ x,
                const float* __restrict__ bias,
                const float* __restrict__ tau,
                const bf16x8* __restrict__ wsw,
                const bf16x8* __restrict__ winsw,
                float* __restrict__ out)
{
    __shared__ float  Ut[Ddim * USTRIDE];   // 86016 B, u transposed [n][i]
    __shared__ bf16_t hbuf[4 * 8 * 64 * 8]; // 32768 B, A-frag chunks (mt,kt)

    const int tid = threadIdx.x;
    const int w   = tid >> 6;   // wave id: handles n-cols [64w, 64w+64)
    const int ln  = tid & 63;
    const int c   = ln & 15;
    const int q   = ln >> 4;
    const int blk = blockIdx.x;
    const int bb  = blk >> 5;            // batch
    const int l0  = (blk & 31) * MROWS;  // first output row (within batch)

    int   ncol[4];
    float itau[4];
#pragma unroll
    for (int nl = 0; nl < 4; ++nl) {
        ncol[nl] = (4 * w + nl) * 16 + c;
        itau[nl] = 1.0f / tau[ncol[nl]];
    }

    // ---------------- phase 1: U = X_window @ W_in + bias ----------------
    bf16x8 bfr[8][4];   // B-fragments, register resident (128 VGPRs)
#pragma unroll
    for (int kt = 0; kt < 8; ++kt)
#pragma unroll
        for (int nl = 0; nl < 4; ++nl)
            bfr[kt][nl] = winsw[(kt * 16 + 4 * w + nl) * 64 + ln];

    f32x4 au[5][4];
#pragma unroll
    for (int nl = 0; nl < 4; ++nl) {
        float bv = bias[ncol[nl]];
#pragma unroll
        for (int mt = 0; mt < 5; ++mt) {
            f32x4 t = {bv, bv, bv, bv};
            au[mt][nl] = t;
        }
    }

    const float* xb = x + bb * (Ldim * Ddim);
#pragma unroll
    for (int kt = 0; kt < 8; ++kt) {
        bf16x8 aF[5];
#pragma unroll
        for (int mt = 0; mt < 5; ++mt) {
            int lrow = l0 - 7 + mt * 16 + c;   // A row m = lane&15 = c
            f32x4 a0 = {0.f, 0.f, 0.f, 0.f};
            f32x4 a1 = {0.f, 0.f, 0.f, 0.f};
            if (lrow >= 0 && lrow < Ldim) {    // zero-pad outside the batch
                const f32x4* p = (const f32x4*)(xb + lrow * Ddim + kt * 32 + q * 8);
                a0 = p[0];
                a1 = p[1];
            }
            bf16x8 av;
#pragma unroll
            for (int jj = 0; jj < 4; ++jj) {
                av[jj]     = (bf16_t)a0[jj];
                av[jj + 4] = (bf16_t)a1[jj];
            }
            aF[mt] = av;
        }
#pragma unroll
        for (int nl = 0; nl < 4; ++nl)
#pragma unroll
            for (int mt = 0; mt < 5; ++mt)
                au[mt][nl] = __builtin_amdgcn_mfma_f32_16x16x32_bf16(
                    aF[mt], bfr[kt][nl], au[mt][nl], 0, 0, 0);
    }

    // store U transposed: row i = mt*16 + 4q + reg is contiguous -> b128
#pragma unroll
    for (int mt = 0; mt < 5; ++mt)
#pragma unroll
        for (int nl = 0; nl < 4; ++nl)
            *(f32x4*)&Ut[ncol[nl] * USTRIDE + mt * 16 + 4 * q] = au[mt][nl];

    __syncthreads();

    // ---------------- phase 2: 8-step recurrence ----------------
#pragma unroll
    for (int kt = 0; kt < 8; ++kt)
#pragma unroll
        for (int nl = 0; nl < 4; ++nl)
            bfr[kt][nl] = wsw[(kt * 16 + 4 * w + nl) * 64 + ln];

    f32x4 h[4][4];   // h in C-layout fp32, register resident
    // t = 0: h = itau * relu(u_0)
#pragma unroll
    for (int mt = 0; mt < 4; ++mt)
#pragma unroll
        for (int nl = 0; nl < 4; ++nl)
#pragma unroll
            for (int r = 0; r < 4; ++r) {
                float u = Ut[ncol[nl] * USTRIDE + mt * 16 + 4 * q + r];
                h[mt][nl][r] = itau[nl] * fmaxf(u, 0.0f);
            }

#pragma unroll 1
    for (int t = 1; t < 8; ++t) {
        // scatter h (C-layout) -> hbuf (bf16 A-fragments)
#pragma unroll
        for (int mt = 0; mt < 4; ++mt)
#pragma unroll
            for (int nl = 0; nl < 4; ++nl) {
                int kk  = ncol[nl];        // this element's k column
                int ktg = kk >> 5;
                int qp  = (kk >> 3) & 3;
                int jj  = kk & 7;
#pragma unroll
                for (int r = 0; r < 4; ++r) {
                    int m = 4 * q + r;     // m & 15
                    hbuf[(mt * 8 + ktg) * 512 + ((qp << 4) + m) * 8 + jj] =
                        (bf16_t)h[mt][nl][r];
                }
            }
        // C-init = u_t (reads Ut, no hazard with hbuf)
        f32x4 acc[4][4];
#pragma unroll
        for (int mt = 0; mt < 4; ++mt)
#pragma unroll
            for (int nl = 0; nl < 4; ++nl)
#pragma unroll
                for (int r = 0; r < 4; ++r)
                    acc[mt][nl][r] =
                        Ut[ncol[nl] * USTRIDE + mt * 16 + 4 * q + r + t];
        __syncthreads();   // hbuf writes visible
#pragma unroll
        for (int kt = 0; kt < 8; ++kt) {
            bf16x8 aF[4];
#pragma unroll
            for (int mt = 0; mt < 4; ++mt)
                aF[mt] = *(const bf16x8*)&hbuf[(mt * 8 + kt) * 512 + ln * 8];
#pragma unroll
            for (int nl = 0; nl < 4; ++nl)
#pragma unroll
                for (int mt = 0; mt < 4; ++mt)
                    acc[mt][nl] = __builtin_amdgcn_mfma_f32_16x16x32_bf16(
                        aF[mt], bfr[kt][nl], acc[mt][nl], 0, 0, 0);
        }
        __syncthreads();   // all reads done before next iter's writes
        // h <- h + itau * (relu(hW + u) - h)
#pragma unroll
        for (int mt = 0; mt < 4; ++mt)
#pragma unroll
            for (int nl = 0; nl < 4; ++nl)
#pragma unroll
                for (int r = 0; r < 4; ++r) {
                    float hh = h[mt][nl][r];
                    float s  = fmaxf(acc[mt][nl][r], 0.0f);
                    h[mt][nl][r] = hh + itau[nl] * (s - hh);
                }
    }

    // epilogue: h (C-layout) -> out fp32
    float* ob = out + (bb * Ldim + l0) * Ddim;
#pragma unroll
    for (int mt = 0; mt < 4; ++mt)
#pragma unroll
        for (int nl = 0; nl < 4; ++nl)
#pragma unroll
            for (int r = 0; r < 4; ++r)
                ob[(mt * 16 + 4 * q + r) * Ddim + ncol[nl]] = h[mt][nl][r];
}

extern "C" void kernel_launch(void* const* d_in, const int* in_sizes, int n_in,
                              void* d_out, int out_size, void* d_ws, size_t ws_size,
                              hipStream_t stream) {
    const float* x            = (const float*)d_in[0];
    const float* weight       = (const float*)d_in[1];
    const float* input_weight = (const float*)d_in[2];
    const float* bias         = (const float*)d_in[3];
    const float* tau          = (const float*)d_in[4];
    (void)in_sizes; (void)n_in; (void)out_size; (void)ws_size;

    bf16_t* wsw   = (bf16_t*)d_ws;
    bf16_t* winsw = wsw + 65536;

    swz_kernel<<<512, 256, 0, stream>>>(weight, input_weight, wsw, winsw);
    rnn_kernel<<<256, 256, 0, stream>>>(x, bias, tau,
                                        (const bf16x8*)wsw, (const bf16x8*)winsw,
                                        (float*)d_out);
}

// Round 2
// 107.967 us; speedup vs baseline: 1.0274x; 1.0274x over previous
//
#include <hip/hip_runtime.h>

typedef __bf16 bf16_t;
typedef __bf16 bf16x8 __attribute__((ext_vector_type(8)));
typedef float  f32x4  __attribute__((ext_vector_type(4)));

#define Ldim 2048
#define Ddim 256
#define MROWS 64

// Build frag-major (B-operand) bf16 copies of weight and input_weight.
// Frag element ((kt*16+nt)*64 + lane)*8 + j  =  W[k=kt*32+(lane>>4)*8+j][n=nt*16+(lane&15)]
// 16 blocks: blockIdx = mat*8 + kt. Each block reads a 32-row slab (32 KB, L1-resident).
__global__ void swz_kernel(const float* __restrict__ w,
                           const float* __restrict__ win,
                           bf16_t* __restrict__ wsw,
                           bf16_t* __restrict__ winsw) {
    int mat = blockIdx.x >> 3, kt = blockIdx.x & 7;
    const float* src = mat ? win : w;
    bf16_t*      dst = mat ? winsw : wsw;
    int ln = threadIdx.x & 63, g = threadIdx.x >> 6;
    int c = ln & 15, q = ln >> 4;
#pragma unroll
    for (int i = 0; i < 4; ++i) {
        int nt = g + 4 * i;
        bf16x8 v;
#pragma unroll
        for (int j = 0; j < 8; ++j)
            v[j] = (bf16_t)src[(kt * 32 + q * 8 + j) * Ddim + nt * 16 + c];
        *(bf16x8*)&dst[((kt * 16 + nt) * 64 + ln) * 8] = v;
    }
}

__global__ __launch_bounds__(256, 1)
void rnn_kernel(const float* __restrict__ x,
                const float* __restrict__ bias,
                const float* __restrict__ tau,
                const bf16x8* __restrict__ wsw,
                const bf16x8* __restrict__ winsw,
                float* __restrict__ out)
{
    // h A-fragments, bit-permuted so the C-layout scatter is bank-conflict-free:
    // chunk (mt,kt) base = (mt*8+kt)*1024 B; element (lane', j) at
    // byte perm(lane')*16 + 2j, perm(lane' = qp<<4|q<<2|r) = r<<4|qp<<2|q.
    __shared__ bf16_t hbuf[4 * 8 * 512];   // 32768 B
    char* hb = (char*)hbuf;

    const int tid = threadIdx.x;
    const int w   = tid >> 6;   // wave: owns n-cols [64w, 64w+64)
    const int ln  = tid & 63;
    const int c   = ln & 15;
    const int q   = ln >> 4;
    const int blk = blockIdx.x;
    const int bb  = blk >> 5;             // batch
    const int l0  = (blk & 31) * MROWS;   // first output row within batch

    int   ncol[4];
    float itau[4];
#pragma unroll
    for (int nl = 0; nl < 4; ++nl) {
        ncol[nl] = (4 * w + nl) * 16 + c;
        itau[nl] = 1.0f / tau[ncol[nl]];
    }

    // ------------- phase 1: au = X_window @ W_in + bias (C layout) -------------
    f32x4 au[5][4];
#pragma unroll
    for (int nl = 0; nl < 4; ++nl) {
        float bv = bias[ncol[nl]];
#pragma unroll
        for (int mt = 0; mt < 5; ++mt) {
            f32x4 t = {bv, bv, bv, bv};
            au[mt][nl] = t;
        }
    }

    const float* xb = x + (long)bb * (Ldim * Ddim);
    const f32x4 zf = {0.f, 0.f, 0.f, 0.f};

    auto loadX = [&](f32x4 (&buf)[5][2], int kt) {
#pragma unroll
        for (int mt = 0; mt < 5; ++mt) {
            int  lrow = l0 - 7 + mt * 16 + c;
            bool ok   = (lrow >= 0) && (lrow < Ldim);
            const f32x4* p = (const f32x4*)(xb + (long)lrow * Ddim + kt * 32 + q * 8);
            buf[mt][0] = ok ? p[0] : zf;
            buf[mt][1] = ok ? p[1] : zf;
        }
    };
    auto loadW = [&](bf16x8 (&wb)[4], int kt) {
#pragma unroll
        for (int nl = 0; nl < 4; ++nl)
            wb[nl] = winsw[(kt * 16 + 4 * w + nl) * 64 + ln];
    };
    auto step1 = [&](const f32x4 (&buf)[5][2], const bf16x8 (&wb)[4]) {
        bf16x8 aF[5];
#pragma unroll
        for (int mt = 0; mt < 5; ++mt)
#pragma unroll
            for (int jj = 0; jj < 4; ++jj) {
                aF[mt][jj]     = (bf16_t)buf[mt][0][jj];
                aF[mt][jj + 4] = (bf16_t)buf[mt][1][jj];
            }
#pragma unroll
        for (int nl = 0; nl < 4; ++nl)
#pragma unroll
            for (int mt = 0; mt < 5; ++mt)
                au[mt][nl] = __builtin_amdgcn_mfma_f32_16x16x32_bf16(
                    aF[mt], wb[nl], au[mt][nl], 0, 0, 0);
    };

    {
        f32x4  x0[5][2], x1[5][2];
        bf16x8 w0[4], w1[4];
        loadX(x0, 0); loadW(w0, 0);
#pragma unroll 1
        for (int kk = 0; kk < 4; ++kk) {
            loadX(x1, 2 * kk + 1); loadW(w1, 2 * kk + 1);
            step1(x0, w0);
            if (kk < 3) { loadX(x0, 2 * kk + 2); loadW(w0, 2 * kk + 2); }
            step1(x1, w1);
        }
    }

    // ------------- phase 2: 8-step recurrence -------------
    bf16x8 bfr[8][4];   // W B-fragments, register resident
#pragma unroll
    for (int kt = 0; kt < 8; ++kt)
#pragma unroll
        for (int nl = 0; nl < 4; ++nl)
            bfr[kt][nl] = wsw[(kt * 16 + 4 * w + nl) * 64 + ln];

    // per-lane scatter byte offsets (t-invariant)
    int offn[4];
#pragma unroll
    for (int nl = 0; nl < 4; ++nl) {
        int kk = ncol[nl];
        offn[nl] = (kk >> 5) * 1024 + ((kk >> 3) & 3) * 64 + q * 16 + (kk & 7) * 2;
    }
    const int permln = (((ln & 3) << 4) | ((ln >> 4) << 2) | ((ln >> 2) & 3)) * 16;
    const int sl     = (ln + 16) & 63;

    f32x4 h[4][4];   // h in C-layout fp32
#pragma unroll
    for (int mt = 0; mt < 4; ++mt)
#pragma unroll
        for (int nl = 0; nl < 4; ++nl)
#pragma unroll
            for (int r = 0; r < 4; ++r)
                h[mt][nl][r] = itau[nl] * fmaxf(au[mt][nl][r], 0.0f);

#pragma unroll 1
    for (int t = 1; t < 8; ++t) {
        // shift au down one row: au[r] <- au[r+1], au[3] <- next quad's (or next tile's) row 0
#pragma unroll
        for (int nl = 0; nl < 4; ++nl) {
            float a[5];
#pragma unroll
            for (int mt = 0; mt < 5; ++mt) a[mt] = __shfl(au[mt][nl][0], sl);
#pragma unroll
            for (int mt = 0; mt < 5; ++mt) {
                float n3 = (q < 3) ? a[mt] : (mt < 4 ? a[mt + 1] : a[mt]);
                f32x4 o = au[mt][nl];
                f32x4 s = {o[1], o[2], o[3], n3};
                au[mt][nl] = s;
            }
        }
        // scatter h (C-layout) -> hbuf (bf16 A-fragments), conflict-free layout
#pragma unroll
        for (int mt = 0; mt < 4; ++mt)
#pragma unroll
            for (int nl = 0; nl < 4; ++nl)
#pragma unroll
                for (int r = 0; r < 4; ++r)
                    *(bf16_t*)(hb + mt * 8192 + r * 256 + offn[nl]) =
                        (bf16_t)h[mt][nl][r];
        __syncthreads();
        f32x4 acc[4][4];
#pragma unroll
        for (int kt = 0; kt < 8; ++kt) {
            bf16x8 aF[4];
#pragma unroll
            for (int mt = 0; mt < 4; ++mt)
                aF[mt] = *(const bf16x8*)(hb + (mt * 8 + kt) * 1024 + permln);
#pragma unroll
            for (int nl = 0; nl < 4; ++nl)
#pragma unroll
                for (int mt = 0; mt < 4; ++mt)
                    acc[mt][nl] = __builtin_amdgcn_mfma_f32_16x16x32_bf16(
                        aF[mt], bfr[kt][nl],
                        (kt == 0) ? au[mt][nl] : acc[mt][nl], 0, 0, 0);
        }
        __syncthreads();   // reads done before next iter's scatter
#pragma unroll
        for (int mt = 0; mt < 4; ++mt)
#pragma unroll
            for (int nl = 0; nl < 4; ++nl)
#pragma unroll
                for (int r = 0; r < 4; ++r) {
                    float hh = h[mt][nl][r];
                    float s  = fmaxf(acc[mt][nl][r], 0.0f);
                    h[mt][nl][r] = hh + itau[nl] * (s - hh);
                }
    }

    // ------------- epilogue -------------
    float* ob = out + ((long)bb * Ldim + l0) * Ddim;
#pragma unroll
    for (int mt = 0; mt < 4; ++mt)
#pragma unroll
        for (int nl = 0; nl < 4; ++nl)
#pragma unroll
            for (int r = 0; r < 4; ++r)
                ob[(mt * 16 + 4 * q + r) * Ddim + ncol[nl]] = h[mt][nl][r];
}

extern "C" void kernel_launch(void* const* d_in, const int* in_sizes, int n_in,
                              void* d_out, int out_size, void* d_ws, size_t ws_size,
                              hipStream_t stream) {
    const float* x            = (const float*)d_in[0];
    const float* weight       = (const float*)d_in[1];
    const float* input_weight = (const float*)d_in[2];
    const float* bias         = (const float*)d_in[3];
    const float* tau          = (const float*)d_in[4];
    (void)in_sizes; (void)n_in; (void)out_size; (void)ws_size;

    bf16_t* wsw   = (bf16_t*)d_ws;
    bf16_t* winsw = wsw + 65536;

    swz_kernel<<<16, 256, 0, stream>>>(weight, input_weight, wsw, winsw);
    rnn_kernel<<<256, 256, 0, stream>>>(x, bias, tau,
                                        (const bf16x8*)wsw, (const bf16x8*)winsw,
                                        (float*)d_out);
}